// Round 21
// baseline (474.750 us; speedup 1.0000x reference)
//
#include <hip/hip_runtime.h>
#include <hip/hip_fp16.h>
#include <math.h>

// Decomposition:
//   t1 = lrelu(feat@W1+b1) (in-wave inside k_Ac)
//   A = t1 @ Wc + bc  (Wc=W2@Wnm_top: h only feeds A)
//   a_s = A@m; bd[v] = feat[v]@qb (fused into k_Ac)
//   w_e = exp(lrelu(a_s[src] + c1*bit + bd[dst] + c0, 0.2))  (fp32; no max)
//   neigh[v] = (sum w_e*A[src] + (sum w_e*bit)*wbit)/sum_w + B[v] + b_nm
//   out = mlp_out(relu(neigh))   (fused into k_nodeout, R21)
// R1: same-address atomicAdd serializes -> block reduce.
// R6: fp16 A gather. R13: MFMA for dense matvecs.
// R7/R8/R14/R16: CSR fill = 1 random dirty 64B line/edge, ~90us flat floor.
// R17-R20: mid-tier is dispatch-count bound; merged hist+prep, scan_c+k_A.
// R21: k_out fused into k_node (k_out was h_node's sole consumer): 16-node
//     tile/block, 4 waves gather into LDS h-tile, wave 0 runs the out-MFMA
//     with B-frags straight from pre-transposed fp16 Wo1hT (L2-hot, no LDS
//     staging -> occupancy preserved). h_node global round-trip eliminated.

typedef _Float16 h2f __attribute__((ext_vector_type(2)));
typedef _Float16 h8  __attribute__((ext_vector_type(8)));
typedef float    f4  __attribute__((ext_vector_type(4)));

static __device__ __forceinline__ float lrelu(float x, float s) {
    return x >= 0.f ? x : s * x;
}

// ---------- k_hp: blk0 sc; blk1..33 Wc,bc; blk34..97 Wo1hT; blk98.. histogram
// sc[0]=c1=wbit@m  sc[1]=c0=b_nm@m  sc[2+k]=qb[k]=Wnm[129+k]@m
__global__ void __launch_bounds__(256) k_hp(const float* __restrict__ W2,
                                            const float* __restrict__ b2,
                                            const float* __restrict__ Wnm,
                                            const float* __restrict__ b_nm,
                                            const float* __restrict__ attn,
                                            const float* __restrict__ Wo1,
                                            __half* __restrict__ Wc,
                                            float* __restrict__ bc,
                                            float* __restrict__ sc,
                                            __half* __restrict__ Wo1hT,
                                            const int* __restrict__ dst,
                                            int* __restrict__ counts, int E) {
    int t = threadIdx.x;
    if (blockIdx.x == 0) {
        __shared__ float red[128];
        float m = (t < 128) ? attn[t] : 0.f;
        if (t < 128) red[t] = Wnm[128 * 128 + t] * m;
        __syncthreads();
        for (int s = 64; s > 0; s >>= 1) { if (t < s) red[t] += red[t + s]; __syncthreads(); }
        if (t == 0) sc[0] = red[0];
        __syncthreads();
        if (t < 128) red[t] = b_nm[t] * m;
        __syncthreads();
        for (int s = 64; s > 0; s >>= 1) { if (t < s) red[t] += red[t + s]; __syncthreads(); }
        if (t == 0) sc[1] = red[0];
        __syncthreads();
        for (int k = 0; k < 16; k++) {
            if (t < 128) red[t] = Wnm[(129 + k) * 128 + t] * m;
            __syncthreads();
            for (int s = 64; s > 0; s >>= 1) { if (t < s) red[t] += red[t + s]; __syncthreads(); }
            if (t == 0) sc[2 + k] = red[0];
            __syncthreads();
        }
    } else if (blockIdx.x <= 33) {
        int idx = (blockIdx.x - 1) * 256 + t;   // 65*128 outputs (row 64 = bias)
        if (idx >= 65 * 128) return;
        int j = idx >> 7, c = idx & 127;
        const float* row = (j < 64) ? &W2[j * 128] : b2;
        float acc = 0.f;
        for (int cp = 0; cp < 128; cp++) acc = fmaf(row[cp], Wnm[cp * 128 + c], acc);
        if (j < 64) Wc[j * 128 + c] = __float2half_rn(acc);
        else bc[c] = acc;
    } else if (blockIdx.x <= 97) {
        int idx = (blockIdx.x - 34) * 256 + t;  // 16384 transposed Wo1 elements
        if (idx < 128 * 128) {
            int c = idx >> 7, k = idx & 127;
            Wo1hT[idx] = __float2half_rn(Wo1[k * 128 + c]);
        }
    } else {
        int e = (blockIdx.x - 98) * 256 + t;
        if (e < E) atomicAdd(&counts[dst[e]], 1);
    }
}

__global__ void k_scan_a(const int* counts, int* row_off, int* partials, int n) {
    __shared__ int sd[256];
    int t = threadIdx.x;
    int base = blockIdx.x * 1024 + t * 4;
    int v0 = (base + 0 < n) ? counts[base + 0] : 0;
    int v1 = (base + 1 < n) ? counts[base + 1] : 0;
    int v2 = (base + 2 < n) ? counts[base + 2] : 0;
    int v3 = (base + 3 < n) ? counts[base + 3] : 0;
    int s = v0 + v1 + v2 + v3;
    sd[t] = s; __syncthreads();
    for (int off = 1; off < 256; off <<= 1) {
        int x = (t >= off) ? sd[t - off] : 0;
        __syncthreads();
        sd[t] += x;
        __syncthreads();
    }
    int run = sd[t] - s;
    if (base + 0 < n) row_off[base + 0] = run; run += v0;
    if (base + 1 < n) row_off[base + 1] = run; run += v1;
    if (base + 2 < n) row_off[base + 2] = run; run += v2;
    if (base + 3 < n) row_off[base + 3] = run;
    if (t == 255) partials[blockIdx.x] = sd[255];
}

// ---------- k_Ac: blocks [0, nscan) -> scan_c fixup; blocks [nscan, ...) -> fused k_A
__global__ void __launch_bounds__(256) k_Ac(int* __restrict__ row_off,
                                            const int* __restrict__ partials,
                                            int* __restrict__ cursor,
                                            const float* __restrict__ feat,
                                            const float* __restrict__ W1,
                                            const float* __restrict__ b1,
                                            const float* __restrict__ sc,
                                            const __half* __restrict__ Wc,
                                            const float* __restrict__ bc,
                                            const float* __restrict__ attn,
                                            __half* __restrict__ Ah,
                                            float* __restrict__ a_s,
                                            float* __restrict__ bd,
                                            int n, int E, int ntiles,
                                            int nscan, int gridA) {
    __shared__ __half Wt[128 * 72];       // Wc^T: Wt[c][k], stride 72
    __shared__ float  W1s[16 * 64];
    __shared__ float  b1s[64];
    __shared__ __half t1s[4][16 * 72];
    int t = threadIdx.x;
    if ((int)blockIdx.x < nscan) {
        int i = blockIdx.x * 256 + t;
        if (i < n) {
            int g = i >> 10;
            int acc = 0;
            for (int j = 0; j < g; j++) acc += partials[j];
            int r = row_off[i] + acc;
            row_off[i] = r;
            cursor[i] = r;
        }
        if (i == 0) row_off[n] = E;
        return;
    }
    int bid = blockIdx.x - nscan;
    for (int idx = t; idx < 64 * 128; idx += 256) {
        int k = idx >> 7, c = idx & 127;
        Wt[c * 72 + k] = Wc[idx];
    }
    for (int idx = t; idx < 1024; idx += 256) W1s[idx] = W1[idx];
    if (t < 64) b1s[t] = b1[t];
    __syncthreads();
    int wave = t >> 6, lane = t & 63;
    int c = lane & 15, q = lane >> 4;
    float attv[8], bcv[8];
#pragma unroll
    for (int ct = 0; ct < 8; ct++) {
        attv[ct] = attn[ct * 16 + c];
        bcv[ct]  = bc[ct * 16 + c];
    }
    float qb[16];
#pragma unroll
    for (int k = 0; k < 16; k++) qb[k] = sc[2 + k];
    __half* myT1 = &t1s[wave][0];
    for (int tile = bid * 4 + wave; tile < ntiles; tile += gridA * 4) {
        int rowbase = tile * 16;
        int rm = min(rowbase + c, n - 1);
        const float4* fr = (const float4*)(feat + (size_t)rm * 16);
        float fv[16];
        *(float4*)&fv[0]  = fr[0];
        *(float4*)&fv[4]  = fr[1];
        *(float4*)&fv[8]  = fr[2];
        *(float4*)&fv[12] = fr[3];
        if (q == 0 && rowbase + c < n) {
            float bacc = 0.f;
#pragma unroll
            for (int k = 0; k < 16; k++) bacc = fmaf(fv[k], qb[k], bacc);
            bd[rowbase + c] = bacc;
        }
        {
            _Float16 tv[16];
#pragma unroll
            for (int jj = 0; jj < 16; jj++) {
                int j = q * 16 + jj;
                float acc = b1s[j];
#pragma unroll
                for (int k = 0; k < 16; k++) acc = fmaf(fv[k], W1s[k * 64 + j], acc);
                tv[jj] = (_Float16)lrelu(acc, 0.1f);
            }
            *(h8*)&myT1[c * 72 + q * 16 + 0] = *(h8*)&tv[0];
            *(h8*)&myT1[c * 72 + q * 16 + 8] = *(h8*)&tv[8];
        }
        h8 af[2];
#pragma unroll
        for (int ks = 0; ks < 2; ks++)
            af[ks] = *(const h8*)&myT1[c * 72 + ks * 32 + q * 8];
        f4 acc[8];
#pragma unroll
        for (int ct = 0; ct < 8; ct++) acc[ct] = (f4)(0.f);
#pragma unroll
        for (int ct = 0; ct < 8; ct++) {
#pragma unroll
            for (int ks = 0; ks < 2; ks++) {
                h8 bf = *(const h8*)&Wt[(ct * 16 + c) * 72 + ks * 32 + q * 8];
                acc[ct] = __builtin_amdgcn_mfma_f32_16x16x32_f16(af[ks], bf, acc[ct], 0, 0, 0);
            }
        }
        int rlim = n - rowbase;
        float s0 = 0.f, s1 = 0.f, s2 = 0.f, s3 = 0.f;
#pragma unroll
        for (int ct = 0; ct < 8; ct++) {
            int col = ct * 16 + c;
            float v0 = acc[ct][0] + bcv[ct];
            float v1 = acc[ct][1] + bcv[ct];
            float v2 = acc[ct][2] + bcv[ct];
            float v3 = acc[ct][3] + bcv[ct];
            if (q * 4 + 0 < rlim) Ah[(size_t)(rowbase + q * 4 + 0) * 128 + col] = __float2half_rn(v0);
            if (q * 4 + 1 < rlim) Ah[(size_t)(rowbase + q * 4 + 1) * 128 + col] = __float2half_rn(v1);
            if (q * 4 + 2 < rlim) Ah[(size_t)(rowbase + q * 4 + 2) * 128 + col] = __float2half_rn(v2);
            if (q * 4 + 3 < rlim) Ah[(size_t)(rowbase + q * 4 + 3) * 128 + col] = __float2half_rn(v3);
            s0 = fmaf(v0, attv[ct], s0);
            s1 = fmaf(v1, attv[ct], s1);
            s2 = fmaf(v2, attv[ct], s2);
            s3 = fmaf(v3, attv[ct], s3);
        }
#pragma unroll
        for (int off = 1; off < 16; off <<= 1) {
            s0 += __shfl_xor(s0, off, 64);
            s1 += __shfl_xor(s1, off, 64);
            s2 += __shfl_xor(s2, off, 64);
            s3 += __shfl_xor(s3, off, 64);
        }
        if (c == 0) {
            if (q * 4 + 0 < rlim) a_s[rowbase + q * 4 + 0] = s0;
            if (q * 4 + 1 < rlim) a_s[rowbase + q * 4 + 1] = s1;
            if (q * 4 + 2 < rlim) a_s[rowbase + q * 4 + 2] = s2;
            if (q * 4 + 3 < rlim) a_s[rowbase + q * 4 + 3] = s3;
        }
    }
}

// ---------- fill CSR: ONE 16B record {src, w, w*bit, pad} per edge (flat) ----------
__global__ void k_fill(const int* __restrict__ src, const int* __restrict__ dst,
                       const float* __restrict__ bit, int* __restrict__ cursor,
                       const float* __restrict__ a_s, const float* __restrict__ bd,
                       const float* __restrict__ sc, float4* __restrict__ recs, int E) {
    int e = blockIdx.x * blockDim.x + threadIdx.x;
    if (e >= E) return;
    int s = src[e], d = dst[e];
    float bv = bit[e];
    float logit = a_s[s] + sc[0] * bv + bd[d] + sc[1];
    float w = __expf(lrelu(logit, 0.2f));
    int p = atomicAdd(&cursor[d], 1);
    recs[p] = make_float4(__int_as_float(s), w, w * bv, 0.f);
}

// ---------- fused node aggregate + out-MLP: 16 nodes/block, 4 waves ----------
// Phase 1: wave w gathers nodes base+4w..base+4w+3 -> LDS h_tile (fp16, stride 136).
// Phase 2: wave 0 runs out-MFMA on the tile; B-frags direct from Wo1hT (L2-hot).
__global__ void __launch_bounds__(256) k_nodeout(const float* __restrict__ feat,
                                                 const float* __restrict__ Wnm,
                                                 const float* __restrict__ b_nm,
                                                 const __half* __restrict__ Ah,
                                                 const int* __restrict__ row_off,
                                                 const float4* __restrict__ recs,
                                                 const __half* __restrict__ Wo1hT,
                                                 const float* __restrict__ bo1,
                                                 const float* __restrict__ Wo2,
                                                 const float* __restrict__ bo2,
                                                 float* __restrict__ out, int n) {
    __shared__ __half h_tile[16 * 136];
    int t = threadIdx.x;
    int wave = t >> 6, lane = t & 63;
    int rowbase = blockIdx.x * 16;
    // phase 1: gather 4 nodes per wave
    for (int i = 0; i < 4; i++) {
        int r = 4 * wave + i;
        int v = min(rowbase + r, n - 1);
        int rs = row_off[v], re = row_off[v + 1];
        const float4* fr = (const float4*)(feat + (size_t)v * 16);
        float fv[16];
        *(float4*)&fv[0]  = fr[0];
        *(float4*)&fv[4]  = fr[1];
        *(float4*)&fv[8]  = fr[2];
        *(float4*)&fv[12] = fr[3];
        float Bx = 0.f, By = 0.f;
#pragma unroll
        for (int k = 0; k < 16; k++) {
            float2 wr = *(const float2*)&Wnm[(129 + k) * 128 + 2 * lane];
            Bx = fmaf(fv[k], wr.x, Bx);
            By = fmaf(fv[k], wr.y, By);
        }
        float hx, hy;
        if (re == rs) {
            hx = 0.f; hy = 0.f;
        } else {
            float ax = 0.f, ay = 0.f, sw = 0.f, swb = 0.f;
#pragma unroll 8
            for (int p = rs; p < re; ++p) {
                float4 rec = recs[p];
                int sv = __float_as_int(rec.x);
                float2 av = __half22float2(*(const __half2*)&Ah[(size_t)sv * 128 + 2 * lane]);
                ax = fmaf(rec.y, av.x, ax);
                ay = fmaf(rec.y, av.y, ay);
                sw += rec.y;
                swb += rec.z;
            }
            float inv = 1.f / sw;
            float2 wb = *(const float2*)&Wnm[128 * 128 + 2 * lane];
            float2 bn = *(const float2*)&b_nm[2 * lane];
            hx = fmaxf(fmaf(swb * inv, wb.x, ax * inv) + Bx + bn.x, 0.f);
            hy = fmaxf(fmaf(swb * inv, wb.y, ay * inv) + By + bn.y, 0.f);
        }
        h2f o; o[0] = (_Float16)hx; o[1] = (_Float16)hy;
        *(h2f*)&h_tile[r * 136 + 2 * lane] = o;
    }
    __syncthreads();
    // phase 2: wave 0 does the out-MLP MFMA for the 16-row tile
    if (wave == 0) {
        int c = lane & 15, q = lane >> 4;
        float b1v[8], w2v[8];
#pragma unroll
        for (int ct = 0; ct < 8; ct++) {
            b1v[ct] = bo1[ct * 16 + c];
            w2v[ct] = Wo2[ct * 16 + c];
        }
        float bias2 = bo2[0];
        h8 af[4];
#pragma unroll
        for (int ks = 0; ks < 4; ks++)
            af[ks] = *(const h8*)&h_tile[c * 136 + ks * 32 + q * 8];
        f4 acc[8];
#pragma unroll
        for (int ct = 0; ct < 8; ct++) acc[ct] = (f4)(0.f);
#pragma unroll
        for (int ct = 0; ct < 8; ct++) {
#pragma unroll
            for (int ks = 0; ks < 4; ks++) {
                h8 bf = *(const h8*)&Wo1hT[(ct * 16 + c) * 128 + ks * 32 + q * 8];
                acc[ct] = __builtin_amdgcn_mfma_f32_16x16x32_f16(af[ks], bf, acc[ct], 0, 0, 0);
            }
        }
        int rlim = n - rowbase;
        float s0 = 0.f, s1 = 0.f, s2 = 0.f, s3 = 0.f;
#pragma unroll
        for (int ct = 0; ct < 8; ct++) {
            s0 = fmaf(lrelu(acc[ct][0] + b1v[ct], 0.1f), w2v[ct], s0);
            s1 = fmaf(lrelu(acc[ct][1] + b1v[ct], 0.1f), w2v[ct], s1);
            s2 = fmaf(lrelu(acc[ct][2] + b1v[ct], 0.1f), w2v[ct], s2);
            s3 = fmaf(lrelu(acc[ct][3] + b1v[ct], 0.1f), w2v[ct], s3);
        }
#pragma unroll
        for (int off = 1; off < 16; off <<= 1) {
            s0 += __shfl_xor(s0, off, 64);
            s1 += __shfl_xor(s1, off, 64);
            s2 += __shfl_xor(s2, off, 64);
            s3 += __shfl_xor(s3, off, 64);
        }
        if (c == 0) {
            if (q * 4 + 0 < rlim) out[rowbase + q * 4 + 0] = bias2 + s0;
            if (q * 4 + 1 < rlim) out[rowbase + q * 4 + 1] = bias2 + s1;
            if (q * 4 + 2 < rlim) out[rowbase + q * 4 + 2] = bias2 + s2;
            if (q * 4 + 3 < rlim) out[rowbase + q * 4 + 3] = bias2 + s3;
        }
    }
}

extern "C" void kernel_launch(void* const* d_in, const int* in_sizes, int n_in,
                              void* d_out, int out_size, void* d_ws, size_t ws_size,
                              hipStream_t stream) {
    const float* feat = (const float*)d_in[0];
    const float* bit  = (const float*)d_in[1];
    const int*   src  = (const int*)d_in[2];
    const int*   dst  = (const int*)d_in[3];
    const float* W1   = (const float*)d_in[4];
    const float* b1   = (const float*)d_in[5];
    const float* W2   = (const float*)d_in[6];
    const float* b2   = (const float*)d_in[7];
    const float* Wnm  = (const float*)d_in[8];
    const float* bnm  = (const float*)d_in[9];
    const float* attn = (const float*)d_in[10];
    const float* Wo1  = (const float*)d_in[11];
    const float* bo1  = (const float*)d_in[12];
    const float* Wo2  = (const float*)d_in[13];
    const float* bo2  = (const float*)d_in[14];
    float* out = (float*)d_out;
    int n = in_sizes[0] / 16;
    int E = in_sizes[2];
    int ntiles = (n + 15) / 16;

    char* wsp = (char*)d_ws;
    size_t off = 0;
    auto alloc = [&](size_t bytes) -> void* {
        void* p = wsp + off;
        off = (off + bytes + 255) & ~(size_t)255;
        return p;
    };
    __half* Ah       = (__half*)alloc((size_t)n * 128 * 2);
    float*  a_s      = (float*)alloc((size_t)n * 4);
    float*  bd       = (float*)alloc((size_t)n * 4);
    int*    counts   = (int*)alloc((size_t)n * 4);
    int*    row_off  = (int*)alloc((size_t)(n + 1) * 4);
    int*    cursor   = (int*)alloc((size_t)n * 4);
    int*    partials = (int*)alloc(8192);
    float*  sc       = (float*)alloc(256);
    __half* Wc       = (__half*)alloc(64 * 128 * 2);
    float*  bc       = (float*)alloc(128 * 4);
    __half* Wo1hT    = (__half*)alloc(128 * 128 * 2);
    float4* recs     = (float4*)alloc((size_t)E * 16);

    int eb256 = (E + 255) / 256;
    int nb256 = (n + 255) / 256;
    int nscan = (n + 1023) / 1024;
    int gridA = 1024;

    hipMemsetAsync(counts, 0, (size_t)n * 4, stream);
    k_hp<<<98 + eb256, 256, 0, stream>>>(W2, b2, Wnm, bnm, attn, Wo1,
                                         Wc, bc, sc, Wo1hT, dst, counts, E);
    k_scan_a<<<nscan, 256, 0, stream>>>(counts, row_off, partials, n);
    k_Ac<<<nb256 + gridA, 256, 0, stream>>>(row_off, partials, cursor,
                                            feat, W1, b1, sc, Wc, bc, attn,
                                            Ah, a_s, bd, n, E, ntiles, nb256, gridA);
    k_fill<<<eb256, 256, 0, stream>>>(src, dst, bit, cursor, a_s, bd, sc, recs, E);
    k_nodeout<<<ntiles, 256, 0, stream>>>(feat, Wnm, bnm, Ah, row_off, recs,
                                          Wo1hT, bo1, Wo2, bo2, out, n);
}